// Round 27
// baseline (79.497 us; speedup 1.0000x reference)
//
#include <hip/hip_runtime.h>

// Polyphase 2x upsample, depthwise 12-tap, reflect pad, fp32.
// out[b,c,oh,ow] = 4 * sum_{m,n=0..5} x[b,c,reflect(q_y+py+m-3),reflect(q_x+px+n-3)]
//                       * filt[11-py-2m][11-px-2n],  oh=2*q_y+py, ow=2*q_x+px
//
// R26->R27: persistent 8-tile block, 3-buffer rotation. R26 (75.95us) blocks
// go load-dark for their back half; R22's deep pipeline failed because its
// re-stage waited on a post-compute barrier (prefetch depth ~1). Now: fixed
// spatial tile per block (goff amortized 8x), bc = z+32t for t=0..7; each
// iter: WAIT(counted) -> bar -> issue loads t+2 (2-deep prefetch) -> tile t.
// vmcnt: 6 (iter0), 22 steady (16 st + 6 ld younger), 16 (last). nt stores +
// XCD swizzle + proven v2f core unchanged.

#define S 40              // slab row stride in words
#define TW 1552           // per-tile buffer: 38x40 = 1520 used, pad tail

typedef float v2f __attribute__((ext_vector_type(2)));
typedef float v4f __attribute__((ext_vector_type(4)));
typedef __attribute__((address_space(3))) void lds_t;
typedef __attribute__((address_space(1))) const void gm_t;

__global__ void filter_prep(const float* __restrict__ filt, float* __restrict__ ws)
{
    int t = threadIdx.x;                 // scalar tap index 0..143
    if (t < 144) {
        int n = t % 6, m = (t / 6) % 6, px = (t / 36) & 1, py = t / 72;
        float f = 4.0f * filt[(11 - py - 2 * m) * 12 + (11 - px - 2 * n)];
        ws[2 * t]     = f;               // duplicated (f,f) pair for v_pk_fma
        ws[2 * t + 1] = f;
    }
}

#define WAIT_BAR(N)                                          \
    asm volatile("s_waitcnt vmcnt(" #N ")" ::: "memory");    \
    __builtin_amdgcn_sched_barrier(0);                       \
    __builtin_amdgcn_s_barrier();                            \
    __builtin_amdgcn_sched_barrier(0);

__global__ __launch_bounds__(256, 4) void upsample2d_kernel(
    const float* __restrict__ x, const v2f* __restrict__ ftp,
    float* __restrict__ out)
{
    __shared__ float s_in[3 * TW];        // 18624 B: 3 rotating tile slabs

    const int tx = threadIdx.x, ty = threadIdx.y;
    const int w    = ty >> 2;             // wave id 0..3
    const int lane = (ty & 3) * 16 + tx;  // HW lane id within wave
    const int z   = blockIdx.z;           // 0..31; bc = z + 32*t, t=0..7

    // ---- XCD-aware spatial swizzle (bijective, proven R26) ----
    const int bid = blockIdx.x + 8 * blockIdx.y;   // 0..63
    const int R   = bid & 7, rr = bid >> 3;
    const int box = (R & 1) * 4 + (rr & 3);        // tile col 0..7
    const int boy = (R >> 1) * 2 + (rr >> 2);      // tile row 0..7

    // ---- block-shared slab offsets: computed ONCE, reused for all 8 tiles ----
    int goff[6];
    #pragma unroll
    for (int k = 0; k < 6; ++k) {
        int j = w * 384 + 64 * k + lane;  // slab word 0..1535
        if (j > 1519) j = 1519;           // tail: dest lands in pad
        int r2 = (j * 1639) >> 16;        // j / 40
        int c = j - r2 * 40;
        int gy = boy * 32 - 3 + r2, gx = box * 32 - 3 + c;
        gy = gy < 0 ? -gy : gy;  gy = gy > 255 ? 510 - gy : gy;
        gx = gx < 0 ? -gx : gx;  gx = gx > 255 ? 510 - gx : gx;
        goff[k] = gy * 256 + gx;
    }

    auto stage = [&](int t, int buf) {
        const float* src = x + (size_t)(z + 32 * t) * 65536;
        float* dst = s_in + buf * TW + w * 384;
        #pragma unroll
        for (int k = 0; k < 6; ++k)
            __builtin_amdgcn_global_load_lds((gm_t*)(src + goff[k]),
                                             (lds_t*)(dst + 64 * k), 4, 0, 0);
    };

    const int xb  = (2 * ty) * S + 2 * tx;   // thread window: slab rows 2ty..2ty+7
    const int OY0 = boy * 64 + 4 * ty;
    const int OX  = box * 64 + 4 * tx;

    // ---- per-tile compute+store: proven v2f core, nt stores ----
    auto tile = [&](int buf, int t) {
        float* oc = out + (size_t)(z + 32 * t) * 262144;
        const int sbase = buf * TW;
        v2f accp[4][2] = {};              // (out[oy][px], out[oy][2+px])
        #pragma unroll
        for (int r8 = 0; r8 < 8; ++r8) {
            const int rb = sbase + xb + r8 * S;
            v2f e[4], o[3];
            #pragma unroll
            for (int j = 0; j < 4; ++j)   // even pairs: cols (2j, 2j+1)
                e[j] = *reinterpret_cast<const v2f*>(&s_in[rb + 2 * j]);
            #pragma unroll
            for (int j = 0; j < 3; ++j) { // odd pairs from LDS (proven form)
                o[j].x = s_in[rb + 2 * j + 1];
                o[j].y = s_in[rb + 2 * j + 2];
            }
            #pragma unroll
            for (int qy = 0; qy < 2; ++qy)
            #pragma unroll
            for (int py = 0; py < 2; ++py) {
                const int m = r8 - qy - py;
                if (m >= 0 && m <= 5) {
                    #pragma unroll
                    for (int px = 0; px < 2; ++px)
                    #pragma unroll
                    for (int n = 0; n < 6; ++n) {
                        const int c = px + n;
                        const v2f xp = (c & 1) ? o[(c - 1) >> 1] : e[c >> 1];
                        const v2f f2 = ftp[((py * 2 + px) * 6 + m) * 6 + n];
                        accp[2 * qy + py][px] =
                            __builtin_elementwise_fma(xp, f2, accp[2 * qy + py][px]);
                    }
                }
            }
        }
        #pragma unroll
        for (int oy = 0; oy < 4; ++oy) {
            v4f v = (v4f){accp[oy][0].x, accp[oy][1].x,
                          accp[oy][0].y, accp[oy][1].y};
            __builtin_nontemporal_store(v,
                reinterpret_cast<v4f*>(&oc[(size_t)(OY0 + oy) * 512 + OX]));
        }
    };

    // ---- 8-tile rolling pipeline, 3 buffers, 2-deep load prefetch ----
    stage(0, 0);                        // L0
    stage(1, 1);                        // L1

    WAIT_BAR(6)                         // L0 done (L1 in flight)
    stage(2, 2);                        // L2: 2 tiles ahead
    tile(0, 0);

    for (int t = 1; t <= 6; ++t) {
        // need L(t); younger ops: st(t-1)=16 + L(t+1)=6 -> vmcnt(22).
        WAIT_BAR(22)
        if (t <= 5) stage(t + 2, (t + 2) % 3);
        tile(t % 3, t);
    }

    WAIT_BAR(16)                        // L7 done (younger: st6 = 16)
    tile(7 % 3, 7);
}

extern "C" void kernel_launch(void* const* d_in, const int* in_sizes, int n_in,
                              void* d_out, int out_size, void* d_ws, size_t ws_size,
                              hipStream_t stream) {
    const float* x    = (const float*)d_in[0];   // (4,64,256,256) fp32
    const float* filt = (const float*)d_in[1];   // (12,12) fp32
    float* out = (float*)d_out;                  // (4,64,512,512) fp32
    float* ws  = (float*)d_ws;                   // 1152 B duplicated filter table

    filter_prep<<<dim3(1), dim3(256), 0, stream>>>(filt, ws);

    dim3 grid(8, 8, 32);    // 8x8 tiles; z=0..31; 8 (batch,channel) per block
    dim3 block(16, 16, 1);
    upsample2d_kernel<<<grid, block, 0, stream>>>(x, (const v2f*)ws, out);
}